// Round 15
// baseline (388.470 us; speedup 1.0000x reference)
//
#include <hip/hip_runtime.h>
#include <hip/hip_bf16.h>

// Problem: B,T,D = 32,4096,128. Masked last/next-observation linear interp.
// v5 (resubmit; round-14 bench was a broker GPUAcquisitionTimeout, no data):
// v4 killed the spill (WRITE exactly 64MiB) but occupancy stuck at 28%
// (2.25 waves/SIMD) with VGPR=80 — still ~87% stalled (VALU 12.6%, HBM 15%).
// Hypothesis: residency is VGPR-capped at the 64/128 HW step. Fix: drop tm
// staging (32 regs) and RELOAD times in the forward sweep (L2-hot; the block
// read those lines moments ago). The reload pointer is laundered through asm
// so GVN can't CSE it with the backward-sweep loads (which would re-create
// the staging and spill). __launch_bounds__(128,8) hard-caps VGPR at 64 ->
// 8 waves/SIMD. Outputs bit-identical to v4.
#define Bq 32
#define Tq 4096
#define Dq 128
#define Lseg 32
#define NSEG (Tq / Lseg)   // 128
#define SRCH 8             // rows probed per search latency-round

__device__ __forceinline__ float bfbits2f(unsigned short u) {
    return __uint_as_float(((unsigned int)u) << 16);
}
__device__ __forceinline__ unsigned short f2hbits(float x) {
    union { _Float16 h; unsigned short s; } cv;
    cv.h = (_Float16)x;
    return cv.s;
}
__device__ __forceinline__ float hbits2f(unsigned short u) {
    union { unsigned short s; _Float16 h; } cv;
    cv.s = u;
    return (float)cv.h;
}
__device__ __forceinline__ float ldval(const void* p, int idx, int f32) {
    if (f32) return ((const float*)p)[idx];
    return bfbits2f(((const unsigned short*)p)[idx]);
}
__device__ __forceinline__ bool ldmask(const void* p, int idx, int mode) {
    switch (mode) {
        case 1:  return ((const int*)p)[idx] != 0;            // int32 0/1
        case 2:  return ((const unsigned short*)p)[idx] != 0; // bf16 0/1.0
        case 3:  return ((const unsigned int*)p)[idx] != 0;   // fp32 0/1.0
        default: return ((const unsigned char*)p)[idx] != 0;  // bool8
    }
}

// ---- named staging registers: pair q = rows 2q (lo16) and 2q+1 (hi16) ----
// pnx: next-observed value (fp16 bits). At masked rows this IS the row's own
// value (bx=v was set before the write). pdt: t_next - t_row (fp16 bits).
// tm is NOT staged (v5): reloaded from L2 in the forward sweep.
#define DECLQ(q) unsigned int pnx_##q, pdt_##q;

// backward sweep steps (visit hi row first, then lo row)
#define BHI(q) { \
    const int rr = 2*(q) + 1; \
    const int idx = base + (sLo + rr) * Dq; \
    float v  = ldval(values, idx, f32); \
    float tm = ldval(times,  idx, f32); \
    bool  m  = ldmask(mask,  idx, mmode); \
    if (m) { bx = v; bt = tm; mbits |= (1u << rr); } \
    pnx_##q = ((unsigned int)f2hbits(bx)) << 16; \
    pdt_##q = ((unsigned int)f2hbits(bt - tm)) << 16; }

#define BLO(q) { \
    const int rr = 2*(q); \
    const int idx = base + (sLo + rr) * Dq; \
    float v  = ldval(values, idx, f32); \
    float tm = ldval(times,  idx, f32); \
    bool  m  = ldmask(mask,  idx, mmode); \
    if (m) { bx = v; bt = tm; mbits |= (1u << rr); } \
    pnx_##q |= (unsigned int)f2hbits(bx); \
    pdt_##q |= (unsigned int)f2hbits(bt - tm); }

// forward sweep. Masked row: v == nx (pnx invariant) -> out=nx, fx=nx, ft=tm.
// Unmasked: out = (fx*dtn + nx*a)/(dtn + a); weights sum to 1, so dtn fp16
// rounding stays within tolerance and denom==0 <=> dtn==0 && a==0.
#define FEMIT(rr, tm, dtn, nx) { \
    bool m = (mbits >> (rr)) & 1u; \
    float ox; \
    if (m) { fx = (nx); ft = (tm); ox = (nx); } \
    else { \
        float a = (tm) - ft; \
        float denom = (dtn) + a; \
        float num = fx * (dtn) + (nx) * a; \
        ox = (denom != 0.f) ? (num / denom) : 0.f; \
    } \
    out[base + (sLo + (rr)) * Dq] = ox; }

#define FLO(q) { \
    float tm  = ldval(tptr, base + (sLo + 2*(q)) * Dq, f32); \
    float dtn = hbits2f((unsigned short)(pdt_##q & 0xFFFFu)); \
    float nx  = hbits2f((unsigned short)(pnx_##q & 0xFFFFu)); \
    FEMIT(2*(q), tm, dtn, nx) }

#define FHI(q) { \
    float tm  = ldval(tptr, base + (sLo + 2*(q) + 1) * Dq, f32); \
    float dtn = hbits2f((unsigned short)(pdt_##q >> 16)); \
    float nx  = hbits2f((unsigned short)(pnx_##q >> 16)); \
    FEMIT(2*(q)+1, tm, dtn, nx) }

// boundary-search probes: mask + SPECULATIVE value/time in one round
#define BPROBE(j) \
    int bm##j; float bv##j, btm##j; { \
        int rj = r + (j); int rc = rj < Tq ? rj : Tq - 1; \
        int idx = base + rc * Dq; \
        bm##j  = (int)ldmask(mask, idx, mmode) & (int)(rj < Tq); \
        bv##j  = ldval(values, idx, f32); \
        btm##j = ldval(times,  idx, f32); }
#define BSEL(j) if (!found && bm##j) { bx = bv##j; bt = btm##j; found = 1; }

#define FPROBE(j) \
    int fm##j; float fv##j, ftm##j; { \
        int rj = r - (j); int rc = rj > 0 ? rj : 0; \
        int idx = base + rc * Dq; \
        fm##j  = (int)ldmask(mask, idx, mmode) & (int)(rj >= 0); \
        fv##j  = ldval(values, idx, f32); \
        ftm##j = ldval(times,  idx, f32); }
#define FSEL(j) if (!found && fm##j) { fx = fv##j; ft = ftm##j; found = 1; }

__global__ __launch_bounds__(128, 8) void interp_kernel(
    const void* __restrict__ values,
    const void* __restrict__ times,
    const void* __restrict__ mask,
    float* __restrict__ out)                 // fp32 output
{
    const int lane = threadIdx.x & 63;

    // ---- in-block dtype detection (wave-uniform, L2-hot) ----
    int mmode, f32;
    {
        const unsigned int* mu = (const unsigned int*)mask;
        int bad_f32 = 0, bad_b16 = 0, off_nz = 0;
        for (int j = lane; j < 1024; j += 64) {       // first 4096 bytes of mask
            unsigned int w = mu[j];
            if (w != 0u && w != 0x3F800000u) bad_f32 = 1;
            unsigned int h0 = w & 0xFFFFu, h1 = w >> 16;
            if ((h0 != 0u && h0 != 0x3F80u) || (h1 != 0u && h1 != 0x3F80u)) bad_b16 = 1;
            if (w & 0xFFFFFF00u) off_nz = 1;
        }
        if      (__ballot(bad_f32) == 0ull) mmode = 3;
        else if (__ballot(bad_b16) == 0ull) mmode = 2;
        else if (__ballot(off_nz)  == 0ull) mmode = 1;
        else                                mmode = 0;

        const unsigned short* tu = (const unsigned short*)times;
        int good = 0;
        for (int k = lane; k < 256; k += 64) {        // even u16s of first 256 elems
            int ex = (tu[2 * k] >> 7) & 0xFF;         // bf16 exponent field
            if (ex >= 118 && ex <= 142) good++;
        }
        for (int off = 32; off; off >>= 1) good += __shfl_xor(good, off, 64);
        f32 = (good < 128) ? 1 : 0;                   // bf16 passes ~100%, fp32 ~10%
    }

    const int b   = blockIdx.x >> 7;          // / NSEG
    const int s   = blockIdx.x & (NSEG - 1);
    const int d   = threadIdx.x;
    const int sLo = s * Lseg;
    const int sHi = sLo + Lseg;
    const int base = b * Tq * Dq + d;

    // laundered times pointer for the forward-sweep reloads: GVN must not
    // CSE them with the backward-sweep loads (that would re-stage tm in
    // 32 regs and blow the 64-VGPR budget).
    const void* tptr = times;
    asm volatile("" : "+s"(tptr));

    // ---- backward boundary: first observation at row >= sHi ----
    float bx = 0.f, bt = 0.f;
    {
        int found = 0;
        for (int r = sHi; r < Tq; r += SRCH) {
            if (__ballot(!found) == 0ull) break;
            BPROBE(0) BPROBE(1) BPROBE(2) BPROBE(3)
            BPROBE(4) BPROBE(5) BPROBE(6) BPROBE(7)
            BSEL(0) BSEL(1) BSEL(2) BSEL(3)
            BSEL(4) BSEL(5) BSEL(6) BSEL(7)
        }
        if (!found) bt = ldval(times, base + (Tq - 1) * Dq, f32); // t_max
    }

    // ---- forward boundary: last observation at row < sLo ----
    float fx = 0.f, ft = 0.f;
    {
        int found = 0;
        for (int r = sLo - 1; r >= 0; r -= SRCH) {
            if (__ballot(!found) == 0ull) break;
            FPROBE(0) FPROBE(1) FPROBE(2) FPROBE(3)
            FPROBE(4) FPROBE(5) FPROBE(6) FPROBE(7)
            FSEL(0) FSEL(1) FSEL(2) FSEL(3)
            FSEL(4) FSEL(5) FSEL(6) FSEL(7)
        }
        if (!found) ft = ldval(times, base, f32);     // times[b,0,d]
    }

    // ---- backward sweep into NAMED registers (no arrays -> no scratch) ----
    DECLQ(0)  DECLQ(1)  DECLQ(2)  DECLQ(3)
    DECLQ(4)  DECLQ(5)  DECLQ(6)  DECLQ(7)
    DECLQ(8)  DECLQ(9)  DECLQ(10) DECLQ(11)
    DECLQ(12) DECLQ(13) DECLQ(14) DECLQ(15)
    unsigned int mbits = 0;

    BHI(15) BLO(15) BHI(14) BLO(14) BHI(13) BLO(13) BHI(12) BLO(12)
    BHI(11) BLO(11) BHI(10) BLO(10) BHI(9)  BLO(9)  BHI(8)  BLO(8)
    BHI(7)  BLO(7)  BHI(6)  BLO(6)  BHI(5)  BLO(5)  BHI(4)  BLO(4)
    BHI(3)  BLO(3)  BHI(2)  BLO(2)  BHI(1)  BLO(1)  BHI(0)  BLO(0)

    // ---- forward sweep: update last-obs state, emit fp32 ----
    FLO(0)  FHI(0)  FLO(1)  FHI(1)  FLO(2)  FHI(2)  FLO(3)  FHI(3)
    FLO(4)  FHI(4)  FLO(5)  FHI(5)  FLO(6)  FHI(6)  FLO(7)  FHI(7)
    FLO(8)  FHI(8)  FLO(9)  FHI(9)  FLO(10) FHI(10) FLO(11) FHI(11)
    FLO(12) FHI(12) FLO(13) FHI(13) FLO(14) FHI(14) FLO(15) FHI(15)
}

extern "C" void kernel_launch(void* const* d_in, const int* in_sizes, int n_in,
                              void* d_out, int out_size, void* d_ws, size_t ws_size,
                              hipStream_t stream) {
    const void* values = d_in[0];
    const void* times  = d_in[1];
    const void* mask   = d_in[2];
    float* out = (float*)d_out;               // reference output dtype = float32
    (void)d_ws; (void)ws_size;

    interp_kernel<<<Bq * NSEG, 128, 0, stream>>>(values, times, mask, out);
}

// Round 17
// 305.012 us; speedup vs baseline: 1.2736x; 1.2736x over previous
//
#include <hip/hip_runtime.h>
#include <hip/hip_bf16.h>

// Problem: B,T,D = 32,4096,128. Masked last/next-observation linear interp.
// v6 (resubmit; round-16 bench was a broker GPUAcquisitionTimeout, no data):
// v5 (launch_bounds 128,8) FAILED — allocator emitted VGPR=32 and spilled
// 188MiB (dur 277, regression). Live state genuinely needs ~80 regs; occupancy
// can't be bought with reg caps. Reverting to v4 math and SPLITTING it into
// two phase kernels through d_ws (boundary record: fx16,ft32,bx16,bt32 =
// 12B/site, 6MiB): search_kernel (detect + both ballot-searches, ~48 regs,
// high occupancy) and main_kernel (detect + ws boundaries + v4 sweep/emit).
// Same total work, bit-identical output; rocprof now reports the per-phase
// durations this session has been guessing at for 3 rounds. Fallback to
// monolithic v4 when ws_size < 6MiB.
#define Bq 32
#define Tq 4096
#define Dq 128
#define Lseg 32
#define NSEG (Tq / Lseg)   // 128
#define NBLK (Bq * NSEG)   // 4096
#define SRCH 8             // rows probed per search latency-round
#define NSITE (Bq * NSEG * Dq)          // 524288 boundary sites
#define WS_NEED (6u * 1024u * 1024u)    // 2x u16[NSITE] + 2x f32[NSITE]

__device__ __forceinline__ float bfbits2f(unsigned short u) {
    return __uint_as_float(((unsigned int)u) << 16);
}
__device__ __forceinline__ unsigned short f2hbits(float x) {
    union { _Float16 h; unsigned short s; } cv;
    cv.h = (_Float16)x;
    return cv.s;
}
__device__ __forceinline__ float hbits2f(unsigned short u) {
    union { unsigned short s; _Float16 h; } cv;
    cv.s = u;
    return (float)cv.h;
}
__device__ __forceinline__ float ldval(const void* p, int idx, int f32) {
    if (f32) return ((const float*)p)[idx];
    return bfbits2f(((const unsigned short*)p)[idx]);
}
__device__ __forceinline__ bool ldmask(const void* p, int idx, int mode) {
    switch (mode) {
        case 1:  return ((const int*)p)[idx] != 0;            // int32 0/1
        case 2:  return ((const unsigned short*)p)[idx] != 0; // bf16 0/1.0
        case 3:  return ((const unsigned int*)p)[idx] != 0;   // fp32 0/1.0
        default: return ((const unsigned char*)p)[idx] != 0;  // bool8
    }
}

// ---- in-block dtype detection (wave-uniform, L2-hot) ----
__device__ __forceinline__ void detect_dtypes(const void* mask, const void* times,
                                              int lane, int& mmode, int& f32) {
    const unsigned int* mu = (const unsigned int*)mask;
    int bad_f32 = 0, bad_b16 = 0, off_nz = 0;
    for (int j = lane; j < 1024; j += 64) {           // first 4096 bytes of mask
        unsigned int w = mu[j];
        if (w != 0u && w != 0x3F800000u) bad_f32 = 1;
        unsigned int h0 = w & 0xFFFFu, h1 = w >> 16;
        if ((h0 != 0u && h0 != 0x3F80u) || (h1 != 0u && h1 != 0x3F80u)) bad_b16 = 1;
        if (w & 0xFFFFFF00u) off_nz = 1;
    }
    if      (__ballot(bad_f32) == 0ull) mmode = 3;
    else if (__ballot(bad_b16) == 0ull) mmode = 2;
    else if (__ballot(off_nz)  == 0ull) mmode = 1;
    else                                mmode = 0;

    const unsigned short* tu = (const unsigned short*)times;
    int good = 0;
    for (int k = lane; k < 256; k += 64) {            // even u16s of first 256 elems
        int ex = (tu[2 * k] >> 7) & 0xFF;             // bf16 exponent field
        if (ex >= 118 && ex <= 142) good++;
    }
    for (int off = 32; off; off >>= 1) good += __shfl_xor(good, off, 64);
    f32 = (good < 128) ? 1 : 0;                       // bf16 ~100%, fp32 ~10%
}

// ---- boundary-search probes: mask + SPECULATIVE value/time in one round ----
#define BPROBE(j) \
    int bm##j; float bv##j, btm##j; { \
        int rj = r + (j); int rc = rj < Tq ? rj : Tq - 1; \
        int idx = base + rc * Dq; \
        bm##j  = (int)ldmask(mask, idx, mmode) & (int)(rj < Tq); \
        bv##j  = ldval(values, idx, f32); \
        btm##j = ldval(times,  idx, f32); }
#define BSEL(j) if (!found && bm##j) { bx = bv##j; bt = btm##j; found = 1; }

#define FPROBE(j) \
    int fm##j; float fv##j, ftm##j; { \
        int rj = r - (j); int rc = rj > 0 ? rj : 0; \
        int idx = base + rc * Dq; \
        fm##j  = (int)ldmask(mask, idx, mmode) & (int)(rj >= 0); \
        fv##j  = ldval(values, idx, f32); \
        ftm##j = ldval(times,  idx, f32); }
#define FSEL(j) if (!found && fm##j) { fx = fv##j; ft = ftm##j; found = 1; }

// ---- named staging registers: pair q = rows 2q (lo16) and 2q+1 (hi16) ----
// pnx: next-observed value (fp16 bits). At masked rows this IS the row's own
// value (bx=v set before the write). pdt: t_next - t_row (fp16 bits).
#define DECLQ(q) float tmL_##q, tmH_##q; unsigned int pnx_##q, pdt_##q;

#define BHI(q) { \
    const int rr = 2*(q) + 1; \
    const int idx = base + (sLo + rr) * Dq; \
    float v  = ldval(values, idx, f32); \
    float tm = ldval(times,  idx, f32); \
    bool  m  = ldmask(mask,  idx, mmode); \
    if (m) { bx = v; bt = tm; mbits |= (1u << rr); } \
    tmH_##q = tm; \
    pnx_##q = ((unsigned int)f2hbits(bx)) << 16; \
    pdt_##q = ((unsigned int)f2hbits(bt - tm)) << 16; }

#define BLO(q) { \
    const int rr = 2*(q); \
    const int idx = base + (sLo + rr) * Dq; \
    float v  = ldval(values, idx, f32); \
    float tm = ldval(times,  idx, f32); \
    bool  m  = ldmask(mask,  idx, mmode); \
    if (m) { bx = v; bt = tm; mbits |= (1u << rr); } \
    tmL_##q = tm; \
    pnx_##q |= (unsigned int)f2hbits(bx); \
    pdt_##q |= (unsigned int)f2hbits(bt - tm); }

// forward sweep. Masked row: v == nx (pnx invariant) -> out=nx, fx=nx, ft=tm.
// Unmasked: out = (fx*dtn + nx*a)/(dtn + a); weights sum to 1, so dtn fp16
// rounding stays within tolerance and denom==0 <=> dtn==0 && a==0.
#define FEMIT(rr, tm, dtn, nx) { \
    bool m = (mbits >> (rr)) & 1u; \
    float ox; \
    if (m) { fx = (nx); ft = (tm); ox = (nx); } \
    else { \
        float a = (tm) - ft; \
        float denom = (dtn) + a; \
        float num = fx * (dtn) + (nx) * a; \
        ox = (denom != 0.f) ? (num / denom) : 0.f; \
    } \
    out[base + (sLo + (rr)) * Dq] = ox; }

#define FLO(q) { \
    float tm  = tmL_##q; \
    float dtn = hbits2f((unsigned short)(pdt_##q & 0xFFFFu)); \
    float nx  = hbits2f((unsigned short)(pnx_##q & 0xFFFFu)); \
    FEMIT(2*(q), tm, dtn, nx) }

#define FHI(q) { \
    float tm  = tmH_##q; \
    float dtn = hbits2f((unsigned short)(pdt_##q >> 16)); \
    float nx  = hbits2f((unsigned short)(pnx_##q >> 16)); \
    FEMIT(2*(q)+1, tm, dtn, nx) }

// ---- v4 search bodies (shared by search_kernel and the fallback) ----
#define BSEARCH_BODY { \
    int found = 0; \
    for (int r = sHi; r < Tq; r += SRCH) { \
        if (__ballot(!found) == 0ull) break; \
        BPROBE(0) BPROBE(1) BPROBE(2) BPROBE(3) \
        BPROBE(4) BPROBE(5) BPROBE(6) BPROBE(7) \
        BSEL(0) BSEL(1) BSEL(2) BSEL(3) \
        BSEL(4) BSEL(5) BSEL(6) BSEL(7) \
    } \
    if (!found) bt = ldval(times, base + (Tq - 1) * Dq, f32); }

#define FSEARCH_BODY { \
    int found = 0; \
    for (int r = sLo - 1; r >= 0; r -= SRCH) { \
        if (__ballot(!found) == 0ull) break; \
        FPROBE(0) FPROBE(1) FPROBE(2) FPROBE(3) \
        FPROBE(4) FPROBE(5) FPROBE(6) FPROBE(7) \
        FSEL(0) FSEL(1) FSEL(2) FSEL(3) \
        FSEL(4) FSEL(5) FSEL(6) FSEL(7) \
    } \
    if (!found) ft = ldval(times, base, f32); }

#define SWEEP_AND_EMIT_BODY { \
    DECLQ(0)  DECLQ(1)  DECLQ(2)  DECLQ(3) \
    DECLQ(4)  DECLQ(5)  DECLQ(6)  DECLQ(7) \
    DECLQ(8)  DECLQ(9)  DECLQ(10) DECLQ(11) \
    DECLQ(12) DECLQ(13) DECLQ(14) DECLQ(15) \
    unsigned int mbits = 0; \
    BHI(15) BLO(15) BHI(14) BLO(14) BHI(13) BLO(13) BHI(12) BLO(12) \
    BHI(11) BLO(11) BHI(10) BLO(10) BHI(9)  BLO(9)  BHI(8)  BLO(8)  \
    BHI(7)  BLO(7)  BHI(6)  BLO(6)  BHI(5)  BLO(5)  BHI(4)  BLO(4)  \
    BHI(3)  BLO(3)  BHI(2)  BLO(2)  BHI(1)  BLO(1)  BHI(0)  BLO(0)  \
    FLO(0)  FHI(0)  FLO(1)  FHI(1)  FLO(2)  FHI(2)  FLO(3)  FHI(3)  \
    FLO(4)  FHI(4)  FLO(5)  FHI(5)  FLO(6)  FHI(6)  FLO(7)  FHI(7)  \
    FLO(8)  FHI(8)  FLO(9)  FHI(9)  FLO(10) FHI(10) FLO(11) FHI(11) \
    FLO(12) FHI(12) FLO(13) FHI(13) FLO(14) FHI(14) FLO(15) FHI(15) }

// ============ phase 1: boundary searches -> ws ============
__global__ __launch_bounds__(128) void search_kernel(
    const void* __restrict__ values,
    const void* __restrict__ times,
    const void* __restrict__ mask,
    unsigned short* __restrict__ fxa, float* __restrict__ fta,
    unsigned short* __restrict__ bxa, float* __restrict__ bta)
{
    const int lane = threadIdx.x & 63;
    int mmode, f32;
    detect_dtypes(mask, times, lane, mmode, f32);

    const int b   = blockIdx.x >> 7;
    const int s   = blockIdx.x & (NSEG - 1);
    const int d   = threadIdx.x;
    const int sLo = s * Lseg;
    const int sHi = sLo + Lseg;
    const int base = b * Tq * Dq + d;

    float bx = 0.f, bt = 0.f;
    BSEARCH_BODY
    float fx = 0.f, ft = 0.f;
    FSEARCH_BODY

    const int si = blockIdx.x * Dq + d;       // coalesced boundary record
    fxa[si] = f2hbits(fx);  fta[si] = ft;
    bxa[si] = f2hbits(bx);  bta[si] = bt;
}

// ============ phase 2: ws boundaries + v4 sweep/emit ============
__global__ __launch_bounds__(128, 3) void main_kernel(
    const void* __restrict__ values,
    const void* __restrict__ times,
    const void* __restrict__ mask,
    float* __restrict__ out,
    const unsigned short* __restrict__ fxa, const float* __restrict__ fta,
    const unsigned short* __restrict__ bxa, const float* __restrict__ bta)
{
    const int lane = threadIdx.x & 63;
    int mmode, f32;
    detect_dtypes(mask, times, lane, mmode, f32);

    const int b   = blockIdx.x >> 7;
    const int s   = blockIdx.x & (NSEG - 1);
    const int d   = threadIdx.x;
    const int sLo = s * Lseg;
    const int base = b * Tq * Dq + d;

    const int si = blockIdx.x * Dq + d;
    float fx = hbits2f(fxa[si]);  float ft = fta[si];
    float bx = hbits2f(bxa[si]);  float bt = bta[si];

    SWEEP_AND_EMIT_BODY
}

// ============ fallback: monolithic v4 (when ws too small) ============
__global__ __launch_bounds__(128, 3) void interp_fallback(
    const void* __restrict__ values,
    const void* __restrict__ times,
    const void* __restrict__ mask,
    float* __restrict__ out)
{
    const int lane = threadIdx.x & 63;
    int mmode, f32;
    detect_dtypes(mask, times, lane, mmode, f32);

    const int b   = blockIdx.x >> 7;
    const int s   = blockIdx.x & (NSEG - 1);
    const int d   = threadIdx.x;
    const int sLo = s * Lseg;
    const int sHi = sLo + Lseg;
    const int base = b * Tq * Dq + d;

    float bx = 0.f, bt = 0.f;
    BSEARCH_BODY
    float fx = 0.f, ft = 0.f;
    FSEARCH_BODY

    SWEEP_AND_EMIT_BODY
}

extern "C" void kernel_launch(void* const* d_in, const int* in_sizes, int n_in,
                              void* d_out, int out_size, void* d_ws, size_t ws_size,
                              hipStream_t stream) {
    const void* values = d_in[0];
    const void* times  = d_in[1];
    const void* mask   = d_in[2];
    float* out = (float*)d_out;               // reference output dtype = float32

    if (d_ws != nullptr && ws_size >= WS_NEED) {
        char* w = (char*)d_ws;
        unsigned short* fxa = (unsigned short*)(w);                    // 1MB
        unsigned short* bxa = (unsigned short*)(w + 1u*1024u*1024u);   // 1MB
        float*          fta = (float*)(w + 2u*1024u*1024u);            // 2MB
        float*          bta = (float*)(w + 4u*1024u*1024u);            // 2MB
        search_kernel<<<NBLK, 128, 0, stream>>>(values, times, mask,
                                                fxa, fta, bxa, bta);
        main_kernel<<<NBLK, 128, 0, stream>>>(values, times, mask, out,
                                              fxa, fta, bxa, bta);
    } else {
        interp_fallback<<<NBLK, 128, 0, stream>>>(values, times, mask, out);
    }
}